// Round 9
// baseline (2430.364 us; speedup 1.0000x reference)
//
#include <hip/hip_runtime.h>
#include <hip/hip_bf16.h>
#include <math.h>

#define N_NODES 20000
#define N_EDGES 100000
#define N_GRAPHS 200
#define NPG 100
#define EPG 500
#define TOPK 125
#define D_IN 64
#define EMB 300
#define H2 600
#define H4 1200
#define NLAYERS 5
#define NOUT 10

// padded dims
#define NPAD 20096      // 157 * 128
#define EMBP 320
#define H2P 640
#define H4P 1216
#define UVM 2432        // stacked u|v output width (2*1216)
#define UVROWS 10112    // 79 * 128 rows per uv chunk

static inline int cdiv(int a, int b) { return (a + b - 1) / b; }

typedef __attribute__((ext_vector_type(8))) short bfrag;
typedef __attribute__((ext_vector_type(4))) float f32x4;

__device__ __forceinline__ ushort f2bf(float f) {
    unsigned u = __builtin_bit_cast(unsigned, f);
    unsigned r = u + 0x7FFFu + ((u >> 16) & 1u);
    return (ushort)(r >> 16);
}
__device__ __forceinline__ float bf2f(ushort h) {
    unsigned u = ((unsigned)h) << 16;
    return __builtin_bit_cast(float, u);
}

template<int NT>
__device__ __forceinline__ void split_planes(float v, ushort& p0, ushort& p1, ushort& p2) {
    p0 = f2bf(v);
    float r = v - bf2f(p0);
    p1 = f2bf(r);
    if (NT == 3) { r -= bf2f(p1); p2 = f2bf(r); } else { p2 = 0; }
}

// async 16B global->LDS copy; LDS dest is wave-uniform base (+ lane*16 by HW)
#define GLOAD_LDS16(gsrc, ldst)                                                   \
    __builtin_amdgcn_global_load_lds(                                             \
        (const __attribute__((address_space(1))) void*)(gsrc),                    \
        (__attribute__((address_space(3))) void*)(ldst), 16, 0, 0)

// ============================================================================
// MFMA GEMM (round-7 proven, byte-identical): A and B staged via
// global_load_lds, 2 barriers per K-step.  BM=128, BN=64 or 128, 4 waves.
// XCD-aware bijective block remap (col-fastest within an XCD's range).
// EPI=0: write fp32 C (+bias, opt relu).  EPI=1: write NT bf16 planes.
// ============================================================================
template<int NT, int RELU, int EPI, int BN>
__launch_bounds__(256)
__global__ void mfma_gemm(const ushort* __restrict__ A0, const ushort* __restrict__ A1,
                          const ushort* __restrict__ A2,
                          const ushort* __restrict__ B0, const ushort* __restrict__ B1,
                          const ushort* __restrict__ B2,
                          const float* __restrict__ bias, int Kp, int Mvalid, int ldc,
                          float* __restrict__ Cf, ushort* __restrict__ C0,
                          ushort* __restrict__ C1, ushort* __restrict__ C2) {
    constexpr int NCOL   = BN / 32;        // per-wave n-fragments (2 or 4)
    constexpr int ABYTES = 8192;           // per plane A tile: 128x32x2B
    constexpr int BBYTES = BN * 64;        // per plane B tile: BNx32x2B
    __shared__ char smem[NT * ABYTES + NT * BBYTES];
    const int tid = threadIdx.x;
    const int wave = tid >> 6, lane = tid & 63;
    const int wr = wave >> 1, wc = wave & 1;

    // ---- bijective XCD remap
    int bx, by;
    {
        const int gx = gridDim.x;
        const int nwg = gx * gridDim.y;
        const int wg = blockIdx.y * gx + blockIdx.x;
        const int q = nwg >> 3, rch = nwg & 7;
        const int xc = wg & 7, k = wg >> 3;
        const int virt = (xc < rch ? xc * (q + 1) : rch * (q + 1) + (xc - rch) * q) + k;
        bx = virt % gx;
        by = virt / gx;
    }
    const long rowbase = (long)by * 128;
    const int n0 = bx * BN;

    const ushort* Ap[3] = {A0, A1, A2};
    const ushort* Bp[3] = {B0, B1, B2};

    f32x4 acc[4][NCOL] = {};

    // staging geometry (swizzled global source, linear LDS dest)
    const int arow0 = wave * 16 + (lane >> 2);
    const int aq = lane & 3;

    for (int k0 = 0; k0 < Kp; k0 += 32) {
#pragma unroll
        for (int p = 0; p < NT; ++p) {
            {
                int r = arow0;
                int q = aq ^ ((r >> 1) & 3);
                GLOAD_LDS16(Ap[p] + (size_t)(rowbase + r) * Kp + k0 + q * 8,
                            smem + p * ABYTES + wave * 1024);
            }
            {
                int r = arow0 + 64;
                int q = aq ^ ((r >> 1) & 3);
                GLOAD_LDS16(Ap[p] + (size_t)(rowbase + r) * Kp + k0 + q * 8,
                            smem + p * ABYTES + 4096 + wave * 1024);
            }
            {
                int r = arow0;
                int q = aq ^ ((r >> 1) & 3);
                GLOAD_LDS16(Bp[p] + (size_t)(n0 + r) * Kp + k0 + q * 8,
                            smem + NT * ABYTES + p * BBYTES + wave * 1024);
            }
            if (BN == 128) {
                int r = arow0 + 64;
                int q = aq ^ ((r >> 1) & 3);
                GLOAD_LDS16(Bp[p] + (size_t)(n0 + r) * Kp + k0 + q * 8,
                            smem + NT * ABYTES + p * BBYTES + 4096 + wave * 1024);
            }
        }
        __syncthreads();

        // ---- fragments + MFMA
        bfrag bfr[NCOL][3];
#pragma unroll
        for (int n = 0; n < NCOL; ++n)
#pragma unroll
            for (int p = 0; p < NT; ++p) {
                int rB = wc * (BN / 2) + n * 16 + (lane & 15);
                int q = (lane >> 4) ^ ((rB >> 1) & 3);
                bfr[n][p] = *(const bfrag*)(smem + NT * ABYTES + p * BBYTES + rB * 64 + q * 16);
            }
#pragma unroll
        for (int m = 0; m < 4; ++m) {
            bfrag afr[3];
#pragma unroll
            for (int p = 0; p < NT; ++p) {
                int rA = wr * 64 + m * 16 + (lane & 15);
                int q = (lane >> 4) ^ ((rA >> 1) & 3);
                afr[p] = *(const bfrag*)(smem + p * ABYTES + rA * 64 + q * 16);
            }
#pragma unroll
            for (int n = 0; n < NCOL; ++n) {
#pragma unroll
                for (int pa = 0; pa < NT; ++pa)
#pragma unroll
                    for (int pb = 0; pb < NT; ++pb)
                        if (pa + pb <= NT - 1)
                            acc[m][n] = __builtin_amdgcn_mfma_f32_16x16x32_bf16(
                                afr[pa], bfr[n][pb], acc[m][n], 0, 0, 0);
            }
        }
        __syncthreads();
    }

    // ---- epilogue.  C/D layout: col = lane&15, row = (lane>>4)*4 + e
    const int colc = lane & 15, rquad = lane >> 4;
#pragma unroll
    for (int m = 0; m < 4; ++m) {
#pragma unroll
        for (int n = 0; n < NCOL; ++n) {
            long grow0 = rowbase + wr * 64 + m * 16 + rquad * 4;
            int gcol = n0 + wc * (BN / 2) + n * 16 + colc;
            bool cvld = gcol < Mvalid;
            float bv = (bias != nullptr && cvld) ? bias[gcol] : 0.f;
#pragma unroll
            for (int e = 0; e < 4; ++e) {
                float v = acc[m][n][e] + bv;
                if (RELU) v = fmaxf(v, 0.f);
                if (!cvld) v = 0.f;
                size_t o = (size_t)(grow0 + e) * ldc + gcol;
                if (EPI == 0) {
                    Cf[o] = v;
                } else {
                    ushort p0, p1, p2;
                    split_planes<NT>(v, p0, p1, p2);
                    C0[o] = p0; C1[o] = p1;
                    if (NT == 3) C2[o] = p2;
                }
            }
        }
    }
}

// ============================================================================
// conversions
// ============================================================================
template<int NT>
__global__ void conv_w(const float* __restrict__ W, int K, int M, int Kp, int Mp,
                       ushort* __restrict__ P0, ushort* __restrict__ P1,
                       ushort* __restrict__ P2) {
    int idx = blockIdx.x * 256 + threadIdx.x;
    if (idx >= Mp * Kp) return;
    int m = idx / Kp, k = idx % Kp;
    float v = (m < M && k < K) ? W[(size_t)k * M + m] : 0.f;
    ushort p0, p1, p2;
    split_planes<NT>(v, p0, p1, p2);
    P0[idx] = p0; P1[idx] = p1;
    if (NT == 3) P2[idx] = p2;
}

// both layer weights (W1: EMB->H2, W2: H2->EMB) in one dispatch
template<int NT>
__global__ void conv_w2(const float* __restrict__ Wa, const float* __restrict__ Wb,
                        ushort* __restrict__ A0, ushort* __restrict__ A1,
                        ushort* __restrict__ A2, ushort* __restrict__ B0,
                        ushort* __restrict__ B1, ushort* __restrict__ B2) {
    int idx = blockIdx.x * 256 + threadIdx.x;
    const int T1 = H2P * EMBP;   // 204800
    if (idx < T1) {
        int m = idx / EMBP, k = idx % EMBP;
        float v = (m < H2 && k < EMB) ? Wa[(size_t)k * H2 + m] : 0.f;
        ushort p0, p1, p2;
        split_planes<NT>(v, p0, p1, p2);
        A0[idx] = p0; A1[idx] = p1;
        if (NT == 3) A2[idx] = p2;
    } else if (idx < 2 * T1) {
        idx -= T1;
        int m = idx / H2P, k = idx % H2P;
        float v = (m < EMB && k < H2) ? Wb[(size_t)k * EMB + m] : 0.f;
        ushort p0, p1, p2;
        split_planes<NT>(v, p0, p1, p2);
        B0[idx] = p0; B1[idx] = p1;
        if (NT == 3) B2[idx] = p2;
    }
}

template<int NT>
__global__ void conv_a(const float* __restrict__ X, int rows_valid, int ldx, int Kv, int Kp,
                       ushort* __restrict__ P0, ushort* __restrict__ P1,
                       ushort* __restrict__ P2, long total) {
    long idx = (long)blockIdx.x * 256 + threadIdx.x;
    if (idx >= total) return;
    int r = (int)(idx / Kp), k = (int)(idx % Kp);
    float v = (r < rows_valid && k < Kv) ? X[(size_t)r * ldx + k] : 0.f;
    ushort p0, p1, p2;
    split_planes<NT>(v, p0, p1, p2);
    P0[idx] = p0; P1[idx] = p1;
    if (NT == 3) P2[idx] = p2;
}

// ============================================================================
// adjacency build (transposed: At[g][src_local][dst_local] += w)
// ============================================================================
__global__ void build_At(const int* __restrict__ src, const int* __restrict__ dst,
                         const float* __restrict__ w, float* __restrict__ At, int E) {
    int e = blockIdx.x * 256 + threadIdx.x;
    if (e >= E) return;
    int s = src[e], d = dst[e];
    int g = s / NPG;
    atomicAdd(&At[(size_t)g * NPG * NPG + (size_t)(s - g * NPG) * NPG + (d - g * NPG)],
              w ? w[e] : 1.f);
}

// ============================================================================
// fused aggregation v2: z = At^T h + (1+eps) h, NT bf16 planes.
// grid = (graph, col-strip of 64); 4 waves x 28 rows (At LDS-padded [100][112]
// so each wave slice is 16B-aligned -> ds_read_b128 broadcasts, not 25 VMEM
// loads per k).  FMA order per (r,c) identical to prior rounds (k ascending,
// one accumulator) -> bit-identical z.
// ============================================================================
template<int NT>
__launch_bounds__(256)
__global__ void agg_gemm(const float* __restrict__ h, const float* __restrict__ At,
                         const float* __restrict__ eps, int l,
                         ushort* __restrict__ z0, ushort* __restrict__ z1,
                         ushort* __restrict__ z2) {
    __shared__ float sAt[NPG * 112];       // 44800 B, rows padded 100->112
    int g = blockIdx.x;
    int strip = blockIdx.y;
    int tid = threadIdx.x;
    int lane = tid & 63;
    int wave = tid >> 6;
    const float* Ag = At + (size_t)g * NPG * NPG;
    const float* hg = h + (size_t)g * NPG * EMBP;

    for (int i = tid; i < NPG * 112; i += 256) {
        int k = i / 112, r = i - k * 112;
        sAt[i] = (r < NPG) ? Ag[k * NPG + r] : 0.f;
    }
    __syncthreads();

    float ep = 1.f + eps[l];
    const int rb = wave * 28;
    int c = strip * 64 + lane;
    bool cv = c < EMB;

    float acc[28];
#pragma unroll
    for (int r = 0; r < 28; ++r) acc[r] = 0.f;

    for (int k = 0; k < NPG; ++k) {
        float hv = cv ? hg[k * EMBP + c] : 0.f;
        const f32x4* a4 = (const f32x4*)(sAt + k * 112 + rb);   // 16B-aligned
#pragma unroll
        for (int q = 0; q < 7; ++q) {
            f32x4 av = a4[q];
            acc[q * 4 + 0] += av[0] * hv;
            acc[q * 4 + 1] += av[1] * hv;
            acc[q * 4 + 2] += av[2] * hv;
            acc[q * 4 + 3] += av[3] * hv;
        }
    }

#pragma unroll
    for (int r = 0; r < 28; ++r) {
        int rl = rb + r;
        if (rl < NPG) {
            int row = g * NPG + rl;
            float z = cv ? acc[r] + ep * hg[rl * EMBP + c] : 0.f;
            ushort p0, p1, p2;
            split_planes<NT>(z, p0, p1, p2);
            size_t o = (size_t)row * EMBP + c;
            z0[o] = p0; z1[o] = p1;
            if (NT == 3) z2[o] = p2;
        }
    }
}

// ============================================================================
// edge score from stacked uv buffer: relu(u[src]+v[dst]+b1) . W2 + b2
// uv row layout: [0:1216) = u, [1216:2432) = v
// ============================================================================
__global__ void edge_score(const float* __restrict__ uv, const float* __restrict__ b1,
                           const float* __restrict__ W2, const float* __restrict__ b2,
                           const int* __restrict__ src, const int* __restrict__ dst,
                           float* __restrict__ score, int E, int node_base) {
    int e = blockIdx.x * 4 + (threadIdx.x >> 6);
    int lane = threadIdx.x & 63;
    if (e >= E) return;
    const float* up = uv + (size_t)(src[e] - node_base) * UVM;
    const float* vp = uv + (size_t)(dst[e] - node_base) * UVM + 1216;
    float acc = 0.f;
    for (int j = lane; j < H4; j += 64) {
        float hj = fmaxf(up[j] + vp[j] + b1[j], 0.f);
        acc += hj * W2[j];
    }
#pragma unroll
    for (int o = 32; o > 0; o >>= 1) acc += __shfl_down(acc, o, 64);
    if (lane == 0) score[e] = acc + b2[0];
}

// ============================================================================
// per-graph top-125 of 500 contiguous edges via bitonic sort
// ============================================================================
__global__ void topk_kernel(const float* __restrict__ score, const int* __restrict__ src,
                            const int* __restrict__ dst, int* __restrict__ c_src,
                            int* __restrict__ c_dst, float* __restrict__ c_w,
                            float* __restrict__ mask) {
    __shared__ float s[512];
    __shared__ short sidx[512];
    int g = blockIdx.x, t = threadIdx.x;
    int base = g * EPG;
    s[t] = (t < EPG) ? score[base + t] : -1e30f;
    sidx[t] = (short)t;
    __syncthreads();
    for (int k = 2; k <= 512; k <<= 1) {
        for (int j = k >> 1; j > 0; j >>= 1) {
            int ixj = t ^ j;
            if (ixj > t) {
                float a = s[t], b = s[ixj];
                bool desc = ((t & k) == 0);
                if (desc ? (a < b) : (a > b)) {
                    s[t] = b; s[ixj] = a;
                    short tmp = sidx[t]; sidx[t] = sidx[ixj]; sidx[ixj] = tmp;
                }
            }
            __syncthreads();
        }
    }
    if (t < TOPK) {
        int e = base + sidx[t];
        int sn = src[e], dn = dst[e];
        c_src[g * TOPK + t] = sn;
        c_dst[g * TOPK + t] = dn;
        c_w[g * TOPK + t] = 1.f / (1.f + expf(-s[t]));
        mask[sn] = 1.f;
        mask[dn] = 1.f;
    }
}

// ============================================================================
// masked mean pool + linear head (h stride EMBP)
// ============================================================================
__global__ void pool_pred(const float* __restrict__ hc, const float* __restrict__ mask,
                          const float* __restrict__ W, const float* __restrict__ b,
                          float* __restrict__ out) {
    int g = blockIdx.x, t = threadIdx.x;
    __shared__ float mloc[NPG];
    __shared__ float pooled[EMB];
    __shared__ float cnt;
    if (t < NPG) mloc[t] = mask[g * NPG + t];
    __syncthreads();
    if (t == 0) {
        float c = 0.f;
        for (int n = 0; n < NPG; ++n) c += mloc[n];
        cnt = fmaxf(c, 1.f);
    }
    __syncthreads();
    for (int c0 = t; c0 < EMB; c0 += 256) {
        float acc = 0.f;
        for (int n = 0; n < NPG; ++n)
            acc += mloc[n] * hc[((size_t)g * NPG + n) * EMBP + c0];
        pooled[c0] = acc / cnt;
    }
    __syncthreads();
    if (t < NOUT) {
        float acc = b[t];
        for (int c0 = 0; c0 < EMB; ++c0) acc += pooled[c0] * W[c0 * NOUT + t];
        out[g * NOUT + t] = acc;
    }
}

// ============================================================================
extern "C" void kernel_launch(void* const* d_in, const int* in_sizes, int n_in,
                              void* d_out, int out_size, void* d_ws, size_t ws_size,
                              hipStream_t stream) {
    const float* x        = (const float*)d_in[0];
    const int*   eidx     = (const int*)d_in[1];
    const float* enc_in_W = (const float*)d_in[4];
    const float* enc_in_b = (const float*)d_in[5];
    const float* enc_W1   = (const float*)d_in[6];
    const float* enc_b1   = (const float*)d_in[7];
    const float* enc_W2   = (const float*)d_in[8];
    const float* enc_b2   = (const float*)d_in[9];
    const float* enc_eps  = (const float*)d_in[10];
    const float* att_W1   = (const float*)d_in[11];
    const float* att_b1   = (const float*)d_in[12];
    const float* att_W2   = (const float*)d_in[13];
    const float* att_b2   = (const float*)d_in[14];
    const float* clf_in_W = (const float*)d_in[15];
    const float* clf_in_b = (const float*)d_in[16];
    const float* clf_W1   = (const float*)d_in[17];
    const float* clf_b1   = (const float*)d_in[18];
    const float* clf_W2   = (const float*)d_in[19];
    const float* clf_b2   = (const float*)d_in[20];
    const float* clf_eps  = (const float*)d_in[21];
    const float* pred_W   = (const float*)d_in[22];
    const float* pred_b   = (const float*)d_in[23];
    float* out = (float*)d_out;

    const int* src = eidx;
    const int* dst = eidx + N_EDGES;

    // ---------------- workspace layout (ws_size = 256 MiB per harness poison) ----
    char* ws = (char*)d_ws;
    constexpr size_t SZ_H    = (size_t)NPAD * EMBP * 4;        //  25,722,880
    constexpr size_t SZ_ZP   = (size_t)NPAD * EMBP * 2;        //  12,861,440 per plane
    constexpr size_t SZ_TP   = (size_t)NPAD * H2P * 2;         //  25,722,880 per plane (FULL)
    constexpr size_t SZ_WSP  = (size_t)H2P * EMBP * 2;         //     409,600 per plane
    constexpr size_t SZ_WUVP = (size_t)UVM * EMBP * 2;         //   1,556,480 per plane

    constexpr size_t OFF_H   = 0;
    constexpr size_t OFF_Z   = OFF_H + SZ_H;                   //  25,722,880
    constexpr size_t OFF_T   = OFF_Z + 3 * SZ_ZP;              //  64,307,200
    constexpr size_t OFF_WSL = OFF_T + 3 * SZ_TP;              // 141,475,840
    constexpr size_t OFF_AT  = OFF_WSL + 6 * SZ_WSP;           // 143,933,440
    constexpr size_t OFF_SC  = OFF_AT + (size_t)N_GRAPHS * NPG * NPG * 4;  // 151,933,440
    constexpr size_t OFF_CW  = OFF_SC + (size_t)N_EDGES * 4;
    constexpr size_t OFF_MK  = OFF_CW + (size_t)N_GRAPHS * TOPK * 4;
    constexpr size_t OFF_CS  = OFF_MK + (size_t)N_NODES * 4;
    constexpr size_t OFF_CD  = OFF_CS + (size_t)N_GRAPHS * TOPK * 4;
    constexpr size_t OFF_UV  = OFF_CD + (size_t)N_GRAPHS * TOPK * 4;       // 152,713,440
    // uvbuf = UVROWS x UVM x 4 = 98,369,536 -> high water 251,082,976 < 256 MiB

    float*  h   = (float*)(ws + OFF_H);
    ushort* z0  = (ushort*)(ws + OFF_Z);
    ushort* z1  = (ushort*)(ws + OFF_Z + SZ_ZP);
    ushort* z2  = (ushort*)(ws + OFF_Z + 2 * SZ_ZP);
    ushort* t0  = (ushort*)(ws + OFF_T);
    ushort* t1  = (ushort*)(ws + OFF_T + SZ_TP);
    ushort* t2  = (ushort*)(ws + OFF_T + 2 * SZ_TP);
    ushort* w0p[3] = {(ushort*)(ws + OFF_WSL), (ushort*)(ws + OFF_WSL + SZ_WSP),
                      (ushort*)(ws + OFF_WSL + 2 * SZ_WSP)};
    ushort* w1p[3] = {(ushort*)(ws + OFF_WSL + 3 * SZ_WSP), (ushort*)(ws + OFF_WSL + 4 * SZ_WSP),
                      (ushort*)(ws + OFF_WSL + 5 * SZ_WSP)};
    float*  At    = (float*)(ws + OFF_AT);
    float*  score = (float*)(ws + OFF_SC);
    float*  c_w   = (float*)(ws + OFF_CW);
    float*  mask  = (float*)(ws + OFF_MK);
    int*    c_src = (int*)(ws + OFF_CS);
    int*    c_dst = (int*)(ws + OFF_CD);
    float*  uvbuf = (float*)(ws + OFF_UV);

    // overlays
    ushort* xp[3] = {z0, z1, z2};              // x planes live in z region pre-layers
    // phase S: wuv planes live in the (dead) t region
    ushort* wuvp[3] = {(ushort*)(ws + OFF_T), (ushort*)(ws + OFF_T + SZ_WUVP),
                       (ushort*)(ws + OFF_T + 2 * SZ_WUVP)};

    // ================= Phase E: encoder (NT=3) =================
    conv_w<3><<<(EMBP * 64) / 256, 256, 0, stream>>>(enc_in_W, D_IN, EMB, 64, EMBP,
                                                     w0p[0], w0p[1], w0p[2]);
    conv_a<3><<<(int)(((long)NPAD * 64) / 256), 256, 0, stream>>>(
        x, N_NODES, D_IN, D_IN, 64, xp[0], xp[1], xp[2], (long)NPAD * 64);
    mfma_gemm<3, 0, 0, 64><<<dim3(EMBP / 64, NPAD / 128), 256, 0, stream>>>(
        xp[0], xp[1], xp[2], w0p[0], w0p[1], w0p[2], enc_in_b, 64, EMB, EMBP,
        h, nullptr, nullptr, nullptr);

    hipMemsetAsync(At, 0, (size_t)N_GRAPHS * NPG * NPG * 4, stream);
    build_At<<<cdiv(N_EDGES, 256), 256, 0, stream>>>(src, dst, nullptr, At, N_EDGES);

    for (int l = 0; l < NLAYERS; ++l) {
        agg_gemm<3><<<dim3(N_GRAPHS, 5), 256, 0, stream>>>(h, At, enc_eps, l, z0, z1, z2);
        conv_w2<3><<<(2 * H2P * EMBP) / 256, 256, 0, stream>>>(
            enc_W1 + (size_t)l * EMB * H2, enc_W2 + (size_t)l * H2 * EMB,
            w0p[0], w0p[1], w0p[2], w1p[0], w1p[1], w1p[2]);
        mfma_gemm<3, 1, 1, 128><<<dim3(H2P / 128, NPAD / 128), 256, 0, stream>>>(
            z0, z1, z2, w0p[0], w0p[1], w0p[2], enc_b1 + l * H2, EMBP, H2, H2P,
            nullptr, t0, t1, t2);
        if (l < NLAYERS - 1)
            mfma_gemm<3, 1, 0, 64><<<dim3(EMBP / 64, NPAD / 128), 256, 0, stream>>>(
                t0, t1, t2, w1p[0], w1p[1], w1p[2], enc_b2 + l * EMB, H2P, EMB, EMBP,
                h, nullptr, nullptr, nullptr);
        else   // final layer: emit bf16 planes (no relu) straight into z region
            mfma_gemm<3, 0, 1, 64><<<dim3(EMBP / 64, NPAD / 128), 256, 0, stream>>>(
                t0, t1, t2, w1p[0], w1p[1], w1p[2], enc_b2 + l * EMB, H2P, EMB, EMBP,
                nullptr, z0, z1, z2);
    }

    // ================= Phase S: edge scores + topk (2 chunks) =================
    // stacked Wu|Wv planes (bias folded into edge_score)
    conv_w<3><<<cdiv(1216 * EMBP, 256), 256, 0, stream>>>(
        att_W1, EMB, H4, EMBP, 1216, wuvp[0], wuvp[1], wuvp[2]);
    conv_w<3><<<cdiv(1216 * EMBP, 256), 256, 0, stream>>>(
        att_W1 + (size_t)EMB * H4, EMB, H4, EMBP, 1216,
        wuvp[0] + (size_t)1216 * EMBP, wuvp[1] + (size_t)1216 * EMBP,
        wuvp[2] + (size_t)1216 * EMBP);
    for (int sc = 0; sc < 2; ++sc) {
        size_t nb0 = (size_t)sc * 10000;           // node base (0 / 10000)
        mfma_gemm<3, 0, 0, 128><<<dim3(UVM / 128, UVROWS / 128), 256, 0, stream>>>(
            z0 + nb0 * EMBP, z1 + nb0 * EMBP, z2 + nb0 * EMBP,
            wuvp[0], wuvp[1], wuvp[2], nullptr, EMBP, UVM, UVM,
            uvbuf, nullptr, nullptr, nullptr);
        edge_score<<<cdiv(N_EDGES / 2, 4), 256, 0, stream>>>(
            uvbuf, att_b1, att_W2, att_b2, src + sc * 50000, dst + sc * 50000,
            score + sc * 50000, N_EDGES / 2, (int)nb0);
    }
    hipMemsetAsync(mask, 0, N_NODES * 4, stream);
    topk_kernel<<<N_GRAPHS, 512, 0, stream>>>(score, src, dst, c_src, c_dst, c_w, mask);

    // ================= Phase C: classifier (NT=2) =================
    conv_w<2><<<(EMBP * 64) / 256, 256, 0, stream>>>(clf_in_W, D_IN, EMB, 64, EMBP,
                                                     w0p[0], w0p[1], w0p[2]);
    conv_a<2><<<(int)(((long)NPAD * 64) / 256), 256, 0, stream>>>(
        x, N_NODES, D_IN, D_IN, 64, xp[0], xp[1], nullptr, (long)NPAD * 64);
    mfma_gemm<2, 0, 0, 64><<<dim3(EMBP / 64, NPAD / 128), 256, 0, stream>>>(
        xp[0], xp[1], nullptr, w0p[0], w0p[1], nullptr, clf_in_b, 64, EMB, EMBP,
        h, nullptr, nullptr, nullptr);

    hipMemsetAsync(At, 0, (size_t)N_GRAPHS * NPG * NPG * 4, stream);
    build_At<<<cdiv(N_GRAPHS * TOPK, 256), 256, 0, stream>>>(c_src, c_dst, c_w, At,
                                                             N_GRAPHS * TOPK);

    for (int l = 0; l < NLAYERS; ++l) {
        agg_gemm<2><<<dim3(N_GRAPHS, 5), 256, 0, stream>>>(h, At, clf_eps, l,
                                                           z0, z1, nullptr);
        conv_w2<2><<<(2 * H2P * EMBP) / 256, 256, 0, stream>>>(
            clf_W1 + (size_t)l * EMB * H2, clf_W2 + (size_t)l * H2 * EMB,
            w0p[0], w0p[1], nullptr, w1p[0], w1p[1], nullptr);
        mfma_gemm<2, 1, 1, 128><<<dim3(H2P / 128, NPAD / 128), 256, 0, stream>>>(
            z0, z1, nullptr, w0p[0], w0p[1], nullptr, clf_b1 + l * H2, EMBP, H2, H2P,
            nullptr, t0, t1, nullptr);
        if (l < NLAYERS - 1)
            mfma_gemm<2, 1, 0, 64><<<dim3(EMBP / 64, NPAD / 128), 256, 0, stream>>>(
                t0, t1, nullptr, w1p[0], w1p[1], nullptr, clf_b2 + l * EMB, H2P, EMB, EMBP,
                h, nullptr, nullptr, nullptr);
        else
            mfma_gemm<2, 0, 0, 64><<<dim3(EMBP / 64, NPAD / 128), 256, 0, stream>>>(
                t0, t1, nullptr, w1p[0], w1p[1], nullptr, clf_b2 + l * EMB, H2P, EMB, EMBP,
                h, nullptr, nullptr, nullptr);
    }

    // ================= pool + head =================
    pool_pred<<<N_GRAPHS, 256, 0, stream>>>(h, mask, pred_W, pred_b, out);
}

// Round 10
// 1899.518 us; speedup vs baseline: 1.2795x; 1.2795x over previous
//
#include <hip/hip_runtime.h>
#include <hip/hip_bf16.h>
#include <math.h>

#define N_NODES 20000
#define N_EDGES 100000
#define N_GRAPHS 200
#define NPG 100
#define EPG 500
#define TOPK 125
#define D_IN 64
#define EMB 300
#define H2 600
#define H4 1200
#define NLAYERS 5
#define NOUT 10

// padded dims
#define NPAD 20096      // 157 * 128
#define EMBP 320
#define H2P 640
#define H4P 1216
#define UVM 2432        // stacked u|v output width (2*1216)
#define UVROWS 10112    // 79 * 128 rows per uv chunk

static inline int cdiv(int a, int b) { return (a + b - 1) / b; }

typedef __attribute__((ext_vector_type(8))) short bfrag;
typedef __attribute__((ext_vector_type(4))) float f32x4;

__device__ __forceinline__ ushort f2bf(float f) {
    unsigned u = __builtin_bit_cast(unsigned, f);
    unsigned r = u + 0x7FFFu + ((u >> 16) & 1u);
    return (ushort)(r >> 16);
}
__device__ __forceinline__ float bf2f(ushort h) {
    unsigned u = ((unsigned)h) << 16;
    return __builtin_bit_cast(float, u);
}

template<int NT>
__device__ __forceinline__ void split_planes(float v, ushort& p0, ushort& p1, ushort& p2) {
    p0 = f2bf(v);
    float r = v - bf2f(p0);
    p1 = f2bf(r);
    if (NT == 3) { r -= bf2f(p1); p2 = f2bf(r); } else { p2 = 0; }
}

// async 16B global->LDS copy; LDS dest is wave-uniform base (+ lane*16 by HW)
#define GLOAD_LDS16(gsrc, ldst)                                                   \
    __builtin_amdgcn_global_load_lds(                                             \
        (const __attribute__((address_space(1))) void*)(gsrc),                    \
        (__attribute__((address_space(3))) void*)(ldst), 16, 0, 0)

// ============================================================================
// MFMA GEMM (round-7 proven, byte-identical): A and B staged via
// global_load_lds, 2 barriers per K-step.  BM=128, BN=64 or 128, 4 waves.
// XCD-aware bijective block remap (col-fastest within an XCD's range).
// EPI=0: write fp32 C (+bias, opt relu).  EPI=1: write NT bf16 planes.
// ============================================================================
template<int NT, int RELU, int EPI, int BN>
__launch_bounds__(256)
__global__ void mfma_gemm(const ushort* __restrict__ A0, const ushort* __restrict__ A1,
                          const ushort* __restrict__ A2,
                          const ushort* __restrict__ B0, const ushort* __restrict__ B1,
                          const ushort* __restrict__ B2,
                          const float* __restrict__ bias, int Kp, int Mvalid, int ldc,
                          float* __restrict__ Cf, ushort* __restrict__ C0,
                          ushort* __restrict__ C1, ushort* __restrict__ C2) {
    constexpr int NCOL   = BN / 32;        // per-wave n-fragments (2 or 4)
    constexpr int ABYTES = 8192;           // per plane A tile: 128x32x2B
    constexpr int BBYTES = BN * 64;        // per plane B tile: BNx32x2B
    __shared__ char smem[NT * ABYTES + NT * BBYTES];
    const int tid = threadIdx.x;
    const int wave = tid >> 6, lane = tid & 63;
    const int wr = wave >> 1, wc = wave & 1;

    // ---- bijective XCD remap
    int bx, by;
    {
        const int gx = gridDim.x;
        const int nwg = gx * gridDim.y;
        const int wg = blockIdx.y * gx + blockIdx.x;
        const int q = nwg >> 3, rch = nwg & 7;
        const int xc = wg & 7, k = wg >> 3;
        const int virt = (xc < rch ? xc * (q + 1) : rch * (q + 1) + (xc - rch) * q) + k;
        bx = virt % gx;
        by = virt / gx;
    }
    const long rowbase = (long)by * 128;
    const int n0 = bx * BN;

    const ushort* Ap[3] = {A0, A1, A2};
    const ushort* Bp[3] = {B0, B1, B2};

    f32x4 acc[4][NCOL] = {};

    // staging geometry (swizzled global source, linear LDS dest)
    const int arow0 = wave * 16 + (lane >> 2);
    const int aq = lane & 3;

    for (int k0 = 0; k0 < Kp; k0 += 32) {
#pragma unroll
        for (int p = 0; p < NT; ++p) {
            {
                int r = arow0;
                int q = aq ^ ((r >> 1) & 3);
                GLOAD_LDS16(Ap[p] + (size_t)(rowbase + r) * Kp + k0 + q * 8,
                            smem + p * ABYTES + wave * 1024);
            }
            {
                int r = arow0 + 64;
                int q = aq ^ ((r >> 1) & 3);
                GLOAD_LDS16(Ap[p] + (size_t)(rowbase + r) * Kp + k0 + q * 8,
                            smem + p * ABYTES + 4096 + wave * 1024);
            }
            {
                int r = arow0;
                int q = aq ^ ((r >> 1) & 3);
                GLOAD_LDS16(Bp[p] + (size_t)(n0 + r) * Kp + k0 + q * 8,
                            smem + NT * ABYTES + p * BBYTES + wave * 1024);
            }
            if (BN == 128) {
                int r = arow0 + 64;
                int q = aq ^ ((r >> 1) & 3);
                GLOAD_LDS16(Bp[p] + (size_t)(n0 + r) * Kp + k0 + q * 8,
                            smem + NT * ABYTES + p * BBYTES + 4096 + wave * 1024);
            }
        }
        __syncthreads();

        // ---- fragments + MFMA
        bfrag bfr[NCOL][3];
#pragma unroll
        for (int n = 0; n < NCOL; ++n)
#pragma unroll
            for (int p = 0; p < NT; ++p) {
                int rB = wc * (BN / 2) + n * 16 + (lane & 15);
                int q = (lane >> 4) ^ ((rB >> 1) & 3);
                bfr[n][p] = *(const bfrag*)(smem + NT * ABYTES + p * BBYTES + rB * 64 + q * 16);
            }
#pragma unroll
        for (int m = 0; m < 4; ++m) {
            bfrag afr[3];
#pragma unroll
            for (int p = 0; p < NT; ++p) {
                int rA = wr * 64 + m * 16 + (lane & 15);
                int q = (lane >> 4) ^ ((rA >> 1) & 3);
                afr[p] = *(const bfrag*)(smem + p * ABYTES + rA * 64 + q * 16);
            }
#pragma unroll
            for (int n = 0; n < NCOL; ++n) {
#pragma unroll
                for (int pa = 0; pa < NT; ++pa)
#pragma unroll
                    for (int pb = 0; pb < NT; ++pb)
                        if (pa + pb <= NT - 1)
                            acc[m][n] = __builtin_amdgcn_mfma_f32_16x16x32_bf16(
                                afr[pa], bfr[n][pb], acc[m][n], 0, 0, 0);
            }
        }
        __syncthreads();
    }

    // ---- epilogue.  C/D layout: col = lane&15, row = (lane>>4)*4 + e
    const int colc = lane & 15, rquad = lane >> 4;
#pragma unroll
    for (int m = 0; m < 4; ++m) {
#pragma unroll
        for (int n = 0; n < NCOL; ++n) {
            long grow0 = rowbase + wr * 64 + m * 16 + rquad * 4;
            int gcol = n0 + wc * (BN / 2) + n * 16 + colc;
            bool cvld = gcol < Mvalid;
            float bv = (bias != nullptr && cvld) ? bias[gcol] : 0.f;
#pragma unroll
            for (int e = 0; e < 4; ++e) {
                float v = acc[m][n][e] + bv;
                if (RELU) v = fmaxf(v, 0.f);
                if (!cvld) v = 0.f;
                size_t o = (size_t)(grow0 + e) * ldc + gcol;
                if (EPI == 0) {
                    Cf[o] = v;
                } else {
                    ushort p0, p1, p2;
                    split_planes<NT>(v, p0, p1, p2);
                    C0[o] = p0; C1[o] = p1;
                    if (NT == 3) C2[o] = p2;
                }
            }
        }
    }
}

// ============================================================================
// conversions
// ============================================================================
template<int NT>
__global__ void conv_w(const float* __restrict__ W, int K, int M, int Kp, int Mp,
                       ushort* __restrict__ P0, ushort* __restrict__ P1,
                       ushort* __restrict__ P2) {
    int idx = blockIdx.x * 256 + threadIdx.x;
    if (idx >= Mp * Kp) return;
    int m = idx / Kp, k = idx % Kp;
    float v = (m < M && k < K) ? W[(size_t)k * M + m] : 0.f;
    ushort p0, p1, p2;
    split_planes<NT>(v, p0, p1, p2);
    P0[idx] = p0; P1[idx] = p1;
    if (NT == 3) P2[idx] = p2;
}

// both layer weights (W1: EMB->H2, W2: H2->EMB) in one dispatch
template<int NT>
__global__ void conv_w2(const float* __restrict__ Wa, const float* __restrict__ Wb,
                        ushort* __restrict__ A0, ushort* __restrict__ A1,
                        ushort* __restrict__ A2, ushort* __restrict__ B0,
                        ushort* __restrict__ B1, ushort* __restrict__ B2) {
    int idx = blockIdx.x * 256 + threadIdx.x;
    const int T1 = H2P * EMBP;   // 204800
    if (idx < T1) {
        int m = idx / EMBP, k = idx % EMBP;
        float v = (m < H2 && k < EMB) ? Wa[(size_t)k * H2 + m] : 0.f;
        ushort p0, p1, p2;
        split_planes<NT>(v, p0, p1, p2);
        A0[idx] = p0; A1[idx] = p1;
        if (NT == 3) A2[idx] = p2;
    } else if (idx < 2 * T1) {
        idx -= T1;
        int m = idx / H2P, k = idx % H2P;
        float v = (m < EMB && k < H2) ? Wb[(size_t)k * EMB + m] : 0.f;
        ushort p0, p1, p2;
        split_planes<NT>(v, p0, p1, p2);
        B0[idx] = p0; B1[idx] = p1;
        if (NT == 3) B2[idx] = p2;
    }
}

template<int NT>
__global__ void conv_a(const float* __restrict__ X, int rows_valid, int ldx, int Kv, int Kp,
                       ushort* __restrict__ P0, ushort* __restrict__ P1,
                       ushort* __restrict__ P2, long total) {
    long idx = (long)blockIdx.x * 256 + threadIdx.x;
    if (idx >= total) return;
    int r = (int)(idx / Kp), k = (int)(idx % Kp);
    float v = (r < rows_valid && k < Kv) ? X[(size_t)r * ldx + k] : 0.f;
    ushort p0, p1, p2;
    split_planes<NT>(v, p0, p1, p2);
    P0[idx] = p0; P1[idx] = p1;
    if (NT == 3) P2[idx] = p2;
}

// ============================================================================
// adjacency build (transposed: At[g][src_local][dst_local] += w)
// ============================================================================
__global__ void build_At(const int* __restrict__ src, const int* __restrict__ dst,
                         const float* __restrict__ w, float* __restrict__ At, int E) {
    int e = blockIdx.x * 256 + threadIdx.x;
    if (e >= E) return;
    int s = src[e], d = dst[e];
    int g = s / NPG;
    atomicAdd(&At[(size_t)g * NPG * NPG + (size_t)(s - g * NPG) * NPG + (d - g * NPG)],
              w ? w[e] : 1.f);
}

// ============================================================================
// fused aggregation v3: round-3 proven inner loop (uniform scalar A loads,
// no predication), but 8 waves per block for latency hiding.
// grid = (graph, col-strip of 64); waves 0..6 own 13 rows, wave 7 owns 9 rows
// (wave-uniform branch -> both loops unpredicated).  Per-(r,c) FMA order
// identical to rounds 3/5/6/7 (k ascending, one accumulator) -> bit-identical z.
// ============================================================================
template<int NT, int ROWS>
__device__ __forceinline__ void agg_rows(const float* __restrict__ hg,
                                         const float* __restrict__ Ag,
                                         int rb, int c, bool cv, float ep, int g,
                                         ushort* __restrict__ z0,
                                         ushort* __restrict__ z1,
                                         ushort* __restrict__ z2) {
    float acc[ROWS];
#pragma unroll
    for (int r = 0; r < ROWS; ++r) acc[r] = 0.f;
#pragma unroll 4
    for (int k = 0; k < NPG; ++k) {
        float hv = cv ? hg[k * EMBP + c] : 0.f;
        const float* ak = Ag + k * NPG + rb;
#pragma unroll
        for (int r = 0; r < ROWS; ++r) acc[r] += ak[r] * hv;
    }
#pragma unroll
    for (int r = 0; r < ROWS; ++r) {
        int row = g * NPG + rb + r;
        float z = cv ? acc[r] + ep * hg[(rb + r) * EMBP + c] : 0.f;
        ushort p0, p1, p2;
        split_planes<NT>(z, p0, p1, p2);
        size_t o = (size_t)row * EMBP + c;
        z0[o] = p0; z1[o] = p1;
        if (NT == 3) z2[o] = p2;
    }
}

template<int NT>
__launch_bounds__(512)
__global__ void agg_gemm(const float* __restrict__ h, const float* __restrict__ At,
                         const float* __restrict__ eps, int l,
                         ushort* __restrict__ z0, ushort* __restrict__ z1,
                         ushort* __restrict__ z2) {
    int g = blockIdx.x;
    int strip = blockIdx.y;
    int lane = threadIdx.x & 63;
    int wave = threadIdx.x >> 6;                       // 0..7
    int rb = __builtin_amdgcn_readfirstlane(wave * 13); // 0,13,...,91
    const float* Ag = At + (size_t)g * NPG * NPG;
    const float* hg = h + (size_t)g * NPG * EMBP;
    float ep = 1.f + eps[l];

    int c = strip * 64 + lane;
    bool cv = c < EMB;

    if (wave < 7)
        agg_rows<NT, 13>(hg, Ag, rb, c, cv, ep, g, z0, z1, z2);
    else
        agg_rows<NT, 9>(hg, Ag, rb, c, cv, ep, g, z0, z1, z2);
}

// ============================================================================
// edge score from stacked uv buffer: relu(u[src]+v[dst]+b1) . W2 + b2
// uv row layout: [0:1216) = u, [1216:2432) = v
// ============================================================================
__global__ void edge_score(const float* __restrict__ uv, const float* __restrict__ b1,
                           const float* __restrict__ W2, const float* __restrict__ b2,
                           const int* __restrict__ src, const int* __restrict__ dst,
                           float* __restrict__ score, int E, int node_base) {
    int e = blockIdx.x * 4 + (threadIdx.x >> 6);
    int lane = threadIdx.x & 63;
    if (e >= E) return;
    const float* up = uv + (size_t)(src[e] - node_base) * UVM;
    const float* vp = uv + (size_t)(dst[e] - node_base) * UVM + 1216;
    float acc = 0.f;
    for (int j = lane; j < H4; j += 64) {
        float hj = fmaxf(up[j] + vp[j] + b1[j], 0.f);
        acc += hj * W2[j];
    }
#pragma unroll
    for (int o = 32; o > 0; o >>= 1) acc += __shfl_down(acc, o, 64);
    if (lane == 0) score[e] = acc + b2[0];
}

// ============================================================================
// per-graph top-125 of 500 contiguous edges via bitonic sort
// ============================================================================
__global__ void topk_kernel(const float* __restrict__ score, const int* __restrict__ src,
                            const int* __restrict__ dst, int* __restrict__ c_src,
                            int* __restrict__ c_dst, float* __restrict__ c_w,
                            float* __restrict__ mask) {
    __shared__ float s[512];
    __shared__ short sidx[512];
    int g = blockIdx.x, t = threadIdx.x;
    int base = g * EPG;
    s[t] = (t < EPG) ? score[base + t] : -1e30f;
    sidx[t] = (short)t;
    __syncthreads();
    for (int k = 2; k <= 512; k <<= 1) {
        for (int j = k >> 1; j > 0; j >>= 1) {
            int ixj = t ^ j;
            if (ixj > t) {
                float a = s[t], b = s[ixj];
                bool desc = ((t & k) == 0);
                if (desc ? (a < b) : (a > b)) {
                    s[t] = b; s[ixj] = a;
                    short tmp = sidx[t]; sidx[t] = sidx[ixj]; sidx[ixj] = tmp;
                }
            }
            __syncthreads();
        }
    }
    if (t < TOPK) {
        int e = base + sidx[t];
        int sn = src[e], dn = dst[e];
        c_src[g * TOPK + t] = sn;
        c_dst[g * TOPK + t] = dn;
        c_w[g * TOPK + t] = 1.f / (1.f + expf(-s[t]));
        mask[sn] = 1.f;
        mask[dn] = 1.f;
    }
}

// ============================================================================
// masked mean pool + linear head (h stride EMBP)
// ============================================================================
__global__ void pool_pred(const float* __restrict__ hc, const float* __restrict__ mask,
                          const float* __restrict__ W, const float* __restrict__ b,
                          float* __restrict__ out) {
    int g = blockIdx.x, t = threadIdx.x;
    __shared__ float mloc[NPG];
    __shared__ float pooled[EMB];
    __shared__ float cnt;
    if (t < NPG) mloc[t] = mask[g * NPG + t];
    __syncthreads();
    if (t == 0) {
        float c = 0.f;
        for (int n = 0; n < NPG; ++n) c += mloc[n];
        cnt = fmaxf(c, 1.f);
    }
    __syncthreads();
    for (int c0 = t; c0 < EMB; c0 += 256) {
        float acc = 0.f;
        for (int n = 0; n < NPG; ++n)
            acc += mloc[n] * hc[((size_t)g * NPG + n) * EMBP + c0];
        pooled[c0] = acc / cnt;
    }
    __syncthreads();
    if (t < NOUT) {
        float acc = b[t];
        for (int c0 = 0; c0 < EMB; ++c0) acc += pooled[c0] * W[c0 * NOUT + t];
        out[g * NOUT + t] = acc;
    }
}

// ============================================================================
extern "C" void kernel_launch(void* const* d_in, const int* in_sizes, int n_in,
                              void* d_out, int out_size, void* d_ws, size_t ws_size,
                              hipStream_t stream) {
    const float* x        = (const float*)d_in[0];
    const int*   eidx     = (const int*)d_in[1];
    const float* enc_in_W = (const float*)d_in[4];
    const float* enc_in_b = (const float*)d_in[5];
    const float* enc_W1   = (const float*)d_in[6];
    const float* enc_b1   = (const float*)d_in[7];
    const float* enc_W2   = (const float*)d_in[8];
    const float* enc_b2   = (const float*)d_in[9];
    const float* enc_eps  = (const float*)d_in[10];
    const float* att_W1   = (const float*)d_in[11];
    const float* att_b1   = (const float*)d_in[12];
    const float* att_W2   = (const float*)d_in[13];
    const float* att_b2   = (const float*)d_in[14];
    const float* clf_in_W = (const float*)d_in[15];
    const float* clf_in_b = (const float*)d_in[16];
    const float* clf_W1   = (const float*)d_in[17];
    const float* clf_b1   = (const float*)d_in[18];
    const float* clf_W2   = (const float*)d_in[19];
    const float* clf_b2   = (const float*)d_in[20];
    const float* clf_eps  = (const float*)d_in[21];
    const float* pred_W   = (const float*)d_in[22];
    const float* pred_b   = (const float*)d_in[23];
    float* out = (float*)d_out;

    const int* src = eidx;
    const int* dst = eidx + N_EDGES;

    // ---------------- workspace layout (ws_size = 256 MiB per harness poison) ----
    char* ws = (char*)d_ws;
    constexpr size_t SZ_H    = (size_t)NPAD * EMBP * 4;        //  25,722,880
    constexpr size_t SZ_ZP   = (size_t)NPAD * EMBP * 2;        //  12,861,440 per plane
    constexpr size_t SZ_TP   = (size_t)NPAD * H2P * 2;         //  25,722,880 per plane (FULL)
    constexpr size_t SZ_WSP  = (size_t)H2P * EMBP * 2;         //     409,600 per plane
    constexpr size_t SZ_WUVP = (size_t)UVM * EMBP * 2;         //   1,556,480 per plane

    constexpr size_t OFF_H   = 0;
    constexpr size_t OFF_Z   = OFF_H + SZ_H;                   //  25,722,880
    constexpr size_t OFF_T   = OFF_Z + 3 * SZ_ZP;              //  64,307,200
    constexpr size_t OFF_WSL = OFF_T + 3 * SZ_TP;              // 141,475,840
    constexpr size_t OFF_AT  = OFF_WSL + 6 * SZ_WSP;           // 143,933,440
    constexpr size_t OFF_SC  = OFF_AT + (size_t)N_GRAPHS * NPG * NPG * 4;  // 151,933,440
    constexpr size_t OFF_CW  = OFF_SC + (size_t)N_EDGES * 4;
    constexpr size_t OFF_MK  = OFF_CW + (size_t)N_GRAPHS * TOPK * 4;
    constexpr size_t OFF_CS  = OFF_MK + (size_t)N_NODES * 4;
    constexpr size_t OFF_CD  = OFF_CS + (size_t)N_GRAPHS * TOPK * 4;
    constexpr size_t OFF_UV  = OFF_CD + (size_t)N_GRAPHS * TOPK * 4;       // 152,713,440
    // uvbuf = UVROWS x UVM x 4 = 98,369,536 -> high water 251,082,976 < 256 MiB

    float*  h   = (float*)(ws + OFF_H);
    ushort* z0  = (ushort*)(ws + OFF_Z);
    ushort* z1  = (ushort*)(ws + OFF_Z + SZ_ZP);
    ushort* z2  = (ushort*)(ws + OFF_Z + 2 * SZ_ZP);
    ushort* t0  = (ushort*)(ws + OFF_T);
    ushort* t1  = (ushort*)(ws + OFF_T + SZ_TP);
    ushort* t2  = (ushort*)(ws + OFF_T + 2 * SZ_TP);
    ushort* w0p[3] = {(ushort*)(ws + OFF_WSL), (ushort*)(ws + OFF_WSL + SZ_WSP),
                      (ushort*)(ws + OFF_WSL + 2 * SZ_WSP)};
    ushort* w1p[3] = {(ushort*)(ws + OFF_WSL + 3 * SZ_WSP), (ushort*)(ws + OFF_WSL + 4 * SZ_WSP),
                      (ushort*)(ws + OFF_WSL + 5 * SZ_WSP)};
    float*  At    = (float*)(ws + OFF_AT);
    float*  score = (float*)(ws + OFF_SC);
    float*  c_w   = (float*)(ws + OFF_CW);
    float*  mask  = (float*)(ws + OFF_MK);
    int*    c_src = (int*)(ws + OFF_CS);
    int*    c_dst = (int*)(ws + OFF_CD);
    float*  uvbuf = (float*)(ws + OFF_UV);

    // overlays
    ushort* xp[3] = {z0, z1, z2};              // x planes live in z region pre-layers
    // phase S: wuv planes live in the (dead) t region
    ushort* wuvp[3] = {(ushort*)(ws + OFF_T), (ushort*)(ws + OFF_T + SZ_WUVP),
                       (ushort*)(ws + OFF_T + 2 * SZ_WUVP)};

    // ================= Phase E: encoder (NT=3) =================
    conv_w<3><<<(EMBP * 64) / 256, 256, 0, stream>>>(enc_in_W, D_IN, EMB, 64, EMBP,
                                                     w0p[0], w0p[1], w0p[2]);
    conv_a<3><<<(int)(((long)NPAD * 64) / 256), 256, 0, stream>>>(
        x, N_NODES, D_IN, D_IN, 64, xp[0], xp[1], xp[2], (long)NPAD * 64);
    mfma_gemm<3, 0, 0, 64><<<dim3(EMBP / 64, NPAD / 128), 256, 0, stream>>>(
        xp[0], xp[1], xp[2], w0p[0], w0p[1], w0p[2], enc_in_b, 64, EMB, EMBP,
        h, nullptr, nullptr, nullptr);

    hipMemsetAsync(At, 0, (size_t)N_GRAPHS * NPG * NPG * 4, stream);
    build_At<<<cdiv(N_EDGES, 256), 256, 0, stream>>>(src, dst, nullptr, At, N_EDGES);

    for (int l = 0; l < NLAYERS; ++l) {
        agg_gemm<3><<<dim3(N_GRAPHS, 5), 512, 0, stream>>>(h, At, enc_eps, l, z0, z1, z2);
        conv_w2<3><<<(2 * H2P * EMBP) / 256, 256, 0, stream>>>(
            enc_W1 + (size_t)l * EMB * H2, enc_W2 + (size_t)l * H2 * EMB,
            w0p[0], w0p[1], w0p[2], w1p[0], w1p[1], w1p[2]);
        mfma_gemm<3, 1, 1, 128><<<dim3(H2P / 128, NPAD / 128), 256, 0, stream>>>(
            z0, z1, z2, w0p[0], w0p[1], w0p[2], enc_b1 + l * H2, EMBP, H2, H2P,
            nullptr, t0, t1, t2);
        if (l < NLAYERS - 1)
            mfma_gemm<3, 1, 0, 64><<<dim3(EMBP / 64, NPAD / 128), 256, 0, stream>>>(
                t0, t1, t2, w1p[0], w1p[1], w1p[2], enc_b2 + l * EMB, H2P, EMB, EMBP,
                h, nullptr, nullptr, nullptr);
        else   // final layer: emit bf16 planes (no relu) straight into z region
            mfma_gemm<3, 0, 1, 64><<<dim3(EMBP / 64, NPAD / 128), 256, 0, stream>>>(
                t0, t1, t2, w1p[0], w1p[1], w1p[2], enc_b2 + l * EMB, H2P, EMB, EMBP,
                nullptr, z0, z1, z2);
    }

    // ================= Phase S: edge scores + topk (2 chunks) =================
    // stacked Wu|Wv planes (bias folded into edge_score)
    conv_w<3><<<cdiv(1216 * EMBP, 256), 256, 0, stream>>>(
        att_W1, EMB, H4, EMBP, 1216, wuvp[0], wuvp[1], wuvp[2]);
    conv_w<3><<<cdiv(1216 * EMBP, 256), 256, 0, stream>>>(
        att_W1 + (size_t)EMB * H4, EMB, H4, EMBP, 1216,
        wuvp[0] + (size_t)1216 * EMBP, wuvp[1] + (size_t)1216 * EMBP,
        wuvp[2] + (size_t)1216 * EMBP);
    for (int sc = 0; sc < 2; ++sc) {
        size_t nb0 = (size_t)sc * 10000;           // node base (0 / 10000)
        mfma_gemm<3, 0, 0, 128><<<dim3(UVM / 128, UVROWS / 128), 256, 0, stream>>>(
            z0 + nb0 * EMBP, z1 + nb0 * EMBP, z2 + nb0 * EMBP,
            wuvp[0], wuvp[1], wuvp[2], nullptr, EMBP, UVM, UVM,
            uvbuf, nullptr, nullptr, nullptr);
        edge_score<<<cdiv(N_EDGES / 2, 4), 256, 0, stream>>>(
            uvbuf, att_b1, att_W2, att_b2, src + sc * 50000, dst + sc * 50000,
            score + sc * 50000, N_EDGES / 2, (int)nb0);
    }
    hipMemsetAsync(mask, 0, N_NODES * 4, stream);
    topk_kernel<<<N_GRAPHS, 512, 0, stream>>>(score, src, dst, c_src, c_dst, c_w, mask);

    // ================= Phase C: classifier (NT=2) =================
    conv_w<2><<<(EMBP * 64) / 256, 256, 0, stream>>>(clf_in_W, D_IN, EMB, 64, EMBP,
                                                     w0p[0], w0p[1], w0p[2]);
    conv_a<2><<<(int)(((long)NPAD * 64) / 256), 256, 0, stream>>>(
        x, N_NODES, D_IN, D_IN, 64, xp[0], xp[1], nullptr, (long)NPAD * 64);
    mfma_gemm<2, 0, 0, 64><<<dim3(EMBP / 64, NPAD / 128), 256, 0, stream>>>(
        xp[0], xp[1], nullptr, w0p[0], w0p[1], nullptr, clf_in_b, 64, EMB, EMBP,
        h, nullptr, nullptr, nullptr);

    hipMemsetAsync(At, 0, (size_t)N_GRAPHS * NPG * NPG * 4, stream);
    build_At<<<cdiv(N_GRAPHS * TOPK, 256), 256, 0, stream>>>(c_src, c_dst, c_w, At,
                                                             N_GRAPHS * TOPK);

    for (int l = 0; l < NLAYERS; ++l) {
        agg_gemm<2><<<dim3(N_GRAPHS, 5), 512, 0, stream>>>(h, At, clf_eps, l,
                                                           z0, z1, nullptr);
        conv_w2<2><<<(2 * H2P * EMBP) / 256, 256, 0, stream>>>(
            clf_W1 + (size_t)l * EMB * H2, clf_W2 + (size_t)l * H2 * EMB,
            w0p[0], w0p[1], nullptr, w1p[0], w1p[1], nullptr);
        mfma_gemm<2, 1, 1, 128><<<dim3(H2P / 128, NPAD / 128), 256, 0, stream>>>(
            z0, z1, nullptr, w0p[0], w0p[1], nullptr, clf_b1 + l * H2, EMBP, H2, H2P,
            nullptr, t0, t1, nullptr);
        if (l < NLAYERS - 1)
            mfma_gemm<2, 1, 0, 64><<<dim3(EMBP / 64, NPAD / 128), 256, 0, stream>>>(
                t0, t1, nullptr, w1p[0], w1p[1], nullptr, clf_b2 + l * EMB, H2P, EMB, EMBP,
                h, nullptr, nullptr, nullptr);
        else
            mfma_gemm<2, 0, 0, 64><<<dim3(EMBP / 64, NPAD / 128), 256, 0, stream>>>(
                t0, t1, nullptr, w1p[0], w1p[1], nullptr, clf_b2 + l * EMB, H2P, EMB, EMBP,
                h, nullptr, nullptr, nullptr);
    }

    // ================= pool + head =================
    pool_pred<<<N_GRAPHS, 256, 0, stream>>>(h, mask, pred_W, pred_b, out);
}

// Round 11
// 1864.573 us; speedup vs baseline: 1.3034x; 1.0187x over previous
//
#include <hip/hip_runtime.h>
#include <hip/hip_bf16.h>
#include <math.h>

#define N_NODES 20000
#define N_EDGES 100000
#define N_GRAPHS 200
#define NPG 100
#define EPG 500
#define TOPK 125
#define D_IN 64
#define EMB 300
#define H2 600
#define H4 1200
#define NLAYERS 5
#define NOUT 10

// padded dims
#define NPAD 20096      // 157 * 128
#define EMBP 320
#define H2P 640
#define H4P 1216
#define UVM 2432        // stacked u|v output width (2*1216)
#define UVROWS 10112    // 79 * 128 rows per uv chunk
#define T1W (H2P * EMBP)   // 204800 elements per weight plane

static inline int cdiv(int a, int b) { return (a + b - 1) / b; }

typedef __attribute__((ext_vector_type(8))) short bfrag;
typedef __attribute__((ext_vector_type(4))) float f32x4;

__device__ __forceinline__ ushort f2bf(float f) {
    unsigned u = __builtin_bit_cast(unsigned, f);
    unsigned r = u + 0x7FFFu + ((u >> 16) & 1u);
    return (ushort)(r >> 16);
}
__device__ __forceinline__ float bf2f(ushort h) {
    unsigned u = ((unsigned)h) << 16;
    return __builtin_bit_cast(float, u);
}

template<int NT>
__device__ __forceinline__ void split_planes(float v, ushort& p0, ushort& p1, ushort& p2) {
    p0 = f2bf(v);
    float r = v - bf2f(p0);
    p1 = f2bf(r);
    if (NT == 3) { r -= bf2f(p1); p2 = f2bf(r); } else { p2 = 0; }
}

// async 16B global->LDS copy; LDS dest is wave-uniform base (+ lane*16 by HW)
#define GLOAD_LDS16(gsrc, ldst)                                                   \
    __builtin_amdgcn_global_load_lds(                                             \
        (const __attribute__((address_space(1))) void*)(gsrc),                    \
        (__attribute__((address_space(3))) void*)(ldst), 16, 0, 0)

// ============================================================================
// MFMA GEMM (round-7 proven, byte-identical): A and B staged via
// global_load_lds, 2 barriers per K-step.  BM=128, BN=64 or 128, 4 waves.
// XCD-aware bijective block remap (col-fastest within an XCD's range).
// EPI=0: write fp32 C (+bias, opt relu).  EPI=1: write NT bf16 planes.
// ============================================================================
template<int NT, int RELU, int EPI, int BN>
__launch_bounds__(256)
__global__ void mfma_gemm(const ushort* __restrict__ A0, const ushort* __restrict__ A1,
                          const ushort* __restrict__ A2,
                          const ushort* __restrict__ B0, const ushort* __restrict__ B1,
                          const ushort* __restrict__ B2,
                          const float* __restrict__ bias, int Kp, int Mvalid, int ldc,
                          float* __restrict__ Cf, ushort* __restrict__ C0,
                          ushort* __restrict__ C1, ushort* __restrict__ C2) {
    constexpr int NCOL   = BN / 32;        // per-wave n-fragments (2 or 4)
    constexpr int ABYTES = 8192;           // per plane A tile: 128x32x2B
    constexpr int BBYTES = BN * 64;        // per plane B tile: BNx32x2B
    __shared__ char smem[NT * ABYTES + NT * BBYTES];
    const int tid = threadIdx.x;
    const int wave = tid >> 6, lane = tid & 63;
    const int wr = wave >> 1, wc = wave & 1;

    // ---- bijective XCD remap
    int bx, by;
    {
        const int gx = gridDim.x;
        const int nwg = gx * gridDim.y;
        const int wg = blockIdx.y * gx + blockIdx.x;
        const int q = nwg >> 3, rch = nwg & 7;
        const int xc = wg & 7, k = wg >> 3;
        const int virt = (xc < rch ? xc * (q + 1) : rch * (q + 1) + (xc - rch) * q) + k;
        bx = virt % gx;
        by = virt / gx;
    }
    const long rowbase = (long)by * 128;
    const int n0 = bx * BN;

    const ushort* Ap[3] = {A0, A1, A2};
    const ushort* Bp[3] = {B0, B1, B2};

    f32x4 acc[4][NCOL] = {};

    // staging geometry (swizzled global source, linear LDS dest)
    const int arow0 = wave * 16 + (lane >> 2);
    const int aq = lane & 3;

    for (int k0 = 0; k0 < Kp; k0 += 32) {
#pragma unroll
        for (int p = 0; p < NT; ++p) {
            {
                int r = arow0;
                int q = aq ^ ((r >> 1) & 3);
                GLOAD_LDS16(Ap[p] + (size_t)(rowbase + r) * Kp + k0 + q * 8,
                            smem + p * ABYTES + wave * 1024);
            }
            {
                int r = arow0 + 64;
                int q = aq ^ ((r >> 1) & 3);
                GLOAD_LDS16(Ap[p] + (size_t)(rowbase + r) * Kp + k0 + q * 8,
                            smem + p * ABYTES + 4096 + wave * 1024);
            }
            {
                int r = arow0;
                int q = aq ^ ((r >> 1) & 3);
                GLOAD_LDS16(Bp[p] + (size_t)(n0 + r) * Kp + k0 + q * 8,
                            smem + NT * ABYTES + p * BBYTES + wave * 1024);
            }
            if (BN == 128) {
                int r = arow0 + 64;
                int q = aq ^ ((r >> 1) & 3);
                GLOAD_LDS16(Bp[p] + (size_t)(n0 + r) * Kp + k0 + q * 8,
                            smem + NT * ABYTES + p * BBYTES + 4096 + wave * 1024);
            }
        }
        __syncthreads();

        // ---- fragments + MFMA
        bfrag bfr[NCOL][3];
#pragma unroll
        for (int n = 0; n < NCOL; ++n)
#pragma unroll
            for (int p = 0; p < NT; ++p) {
                int rB = wc * (BN / 2) + n * 16 + (lane & 15);
                int q = (lane >> 4) ^ ((rB >> 1) & 3);
                bfr[n][p] = *(const bfrag*)(smem + NT * ABYTES + p * BBYTES + rB * 64 + q * 16);
            }
#pragma unroll
        for (int m = 0; m < 4; ++m) {
            bfrag afr[3];
#pragma unroll
            for (int p = 0; p < NT; ++p) {
                int rA = wr * 64 + m * 16 + (lane & 15);
                int q = (lane >> 4) ^ ((rA >> 1) & 3);
                afr[p] = *(const bfrag*)(smem + p * ABYTES + rA * 64 + q * 16);
            }
#pragma unroll
            for (int n = 0; n < NCOL; ++n) {
#pragma unroll
                for (int pa = 0; pa < NT; ++pa)
#pragma unroll
                    for (int pb = 0; pb < NT; ++pb)
                        if (pa + pb <= NT - 1)
                            acc[m][n] = __builtin_amdgcn_mfma_f32_16x16x32_bf16(
                                afr[pa], bfr[n][pb], acc[m][n], 0, 0, 0);
            }
        }
        __syncthreads();
    }

    // ---- epilogue.  C/D layout: col = lane&15, row = (lane>>4)*4 + e
    const int colc = lane & 15, rquad = lane >> 4;
#pragma unroll
    for (int m = 0; m < 4; ++m) {
#pragma unroll
        for (int n = 0; n < NCOL; ++n) {
            long grow0 = rowbase + wr * 64 + m * 16 + rquad * 4;
            int gcol = n0 + wc * (BN / 2) + n * 16 + colc;
            bool cvld = gcol < Mvalid;
            float bv = (bias != nullptr && cvld) ? bias[gcol] : 0.f;
#pragma unroll
            for (int e = 0; e < 4; ++e) {
                float v = acc[m][n][e] + bv;
                if (RELU) v = fmaxf(v, 0.f);
                if (!cvld) v = 0.f;
                size_t o = (size_t)(grow0 + e) * ldc + gcol;
                if (EPI == 0) {
                    Cf[o] = v;
                } else {
                    ushort p0, p1, p2;
                    split_planes<NT>(v, p0, p1, p2);
                    C0[o] = p0; C1[o] = p1;
                    if (NT == 3) C2[o] = p2;
                }
            }
        }
    }
}

// ============================================================================
// conversions
// ============================================================================
template<int NT>
__global__ void conv_w(const float* __restrict__ W, int K, int M, int Kp, int Mp,
                       ushort* __restrict__ P0, ushort* __restrict__ P1,
                       ushort* __restrict__ P2) {
    int idx = blockIdx.x * 256 + threadIdx.x;
    if (idx >= Mp * Kp) return;
    int m = idx / Kp, k = idx % Kp;
    float v = (m < M && k < K) ? W[(size_t)k * M + m] : 0.f;
    ushort p0, p1, p2;
    split_planes<NT>(v, p0, p1, p2);
    P0[idx] = p0; P1[idx] = p1;
    if (NT == 3) P2[idx] = p2;
}

// ALL layers' W1+W2 for one stack in a single dispatch.
// wall layout per layer l: [NT planes W1 (T1W each)][NT planes W2 (T1W each)]
template<int NT>
__global__ void conv_stack(const float* __restrict__ W1s, const float* __restrict__ W2s,
                           ushort* __restrict__ wall) {
    int idx = blockIdx.x * 256 + threadIdx.x;
    const int TOT = NLAYERS * 2 * T1W;
    if (idx >= TOT) return;
    int half = idx / (NLAYERS * T1W);       // 0 = W1, 1 = W2
    int r = idx - half * (NLAYERS * T1W);
    int l = r / T1W, e = r - l * T1W;
    float v;
    if (half == 0) {
        int m = e / EMBP, k = e - m * EMBP;
        v = (m < H2 && k < EMB) ? W1s[(size_t)l * EMB * H2 + (size_t)k * H2 + m] : 0.f;
    } else {
        int m = e / H2P, k = e - m * H2P;
        v = (m < EMB && k < H2) ? W2s[(size_t)l * H2 * EMB + (size_t)k * EMB + m] : 0.f;
    }
    ushort p0, p1, p2;
    split_planes<NT>(v, p0, p1, p2);
    size_t base = (size_t)l * (2 * NT * T1W) + (size_t)half * (NT * T1W) + e;
    wall[base] = p0;
    wall[base + T1W] = p1;
    if (NT == 3) wall[base + 2 * T1W] = p2;
}

// stacked Wu|Wv conversion in one dispatch (NT=3)
__global__ void conv_uv(const float* __restrict__ W, ushort* __restrict__ P0,
                        ushort* __restrict__ P1, ushort* __restrict__ P2) {
    int idx = blockIdx.x * 256 + threadIdx.x;
    if (idx >= UVM * EMBP) return;
    int m = idx / EMBP, k = idx - m * EMBP;
    int half = m >= 1216;
    int mm = m - (half ? 1216 : 0);
    float v = (mm < H4 && k < EMB)
                  ? W[((size_t)k + (half ? EMB : 0)) * H4 + mm] : 0.f;
    ushort p0, p1, p2;
    split_planes<3>(v, p0, p1, p2);
    P0[idx] = p0; P1[idx] = p1; P2[idx] = p2;
}

template<int NT>
__global__ void conv_a(const float* __restrict__ X, int rows_valid, int ldx, int Kv, int Kp,
                       ushort* __restrict__ P0, ushort* __restrict__ P1,
                       ushort* __restrict__ P2, long total) {
    long idx = (long)blockIdx.x * 256 + threadIdx.x;
    if (idx >= total) return;
    int r = (int)(idx / Kp), k = (int)(idx % Kp);
    float v = (r < rows_valid && k < Kv) ? X[(size_t)r * ldx + k] : 0.f;
    ushort p0, p1, p2;
    split_planes<NT>(v, p0, p1, p2);
    P0[idx] = p0; P1[idx] = p1;
    if (NT == 3) P2[idx] = p2;
}

// ============================================================================
// adjacency build (transposed: At[g][src_local][dst_local] += w)
// ============================================================================
__global__ void build_At(const int* __restrict__ src, const int* __restrict__ dst,
                         const float* __restrict__ w, float* __restrict__ At, int E) {
    int e = blockIdx.x * 256 + threadIdx.x;
    if (e >= E) return;
    int s = src[e], d = dst[e];
    int g = s / NPG;
    atomicAdd(&At[(size_t)g * NPG * NPG + (size_t)(s - g * NPG) * NPG + (d - g * NPG)],
              w ? w[e] : 1.f);
}

// ============================================================================
// fused aggregation v4: round-10 structure (8 waves, uniform scalar A loads,
// wave-uniform 13/9 row split) + float2 column vectorization on the first two
// strips (cols [0,128) and [128,256)); strip 2 = cols [256,320) keeps the
// round-10 VW=1 path (incl. c<EMB gating).  Per-(r,c) FMA order identical
// (k ascending, one accumulator) -> bit-identical z.
// ============================================================================
template<int NT, int ROWS, int VW>
__device__ __forceinline__ void agg_rows(const float* __restrict__ hg,
                                         const float* __restrict__ Ag,
                                         int rb, int c0, float ep, int g,
                                         ushort* __restrict__ z0,
                                         ushort* __restrict__ z1,
                                         ushort* __restrict__ z2) {
    float acc[ROWS][VW];
#pragma unroll
    for (int r = 0; r < ROWS; ++r)
#pragma unroll
        for (int w = 0; w < VW; ++w) acc[r][w] = 0.f;
    const bool cv = (VW == 2) ? true : (c0 < EMB);
#pragma unroll 4
    for (int k = 0; k < NPG; ++k) {
        float hv[VW];
        if (VW == 2) {
            float2 t = *(const float2*)(hg + (size_t)k * EMBP + c0);
            hv[0] = t.x; hv[1] = t.y;
        } else {
            hv[0] = cv ? hg[(size_t)k * EMBP + c0] : 0.f;
        }
        const float* ak = Ag + k * NPG + rb;
#pragma unroll
        for (int r = 0; r < ROWS; ++r)
#pragma unroll
            for (int w = 0; w < VW; ++w) acc[r][w] += ak[r] * hv[w];
    }
#pragma unroll
    for (int r = 0; r < ROWS; ++r) {
        int row = g * NPG + rb + r;
        size_t o = (size_t)row * EMBP + c0;
        ushort p0[VW], p1[VW], p2[VW];
#pragma unroll
        for (int w = 0; w < VW; ++w) {
            float z = cv ? acc[r][w] + ep * hg[(size_t)(rb + r) * EMBP + c0 + w] : 0.f;
            split_planes<NT>(z, p0[w], p1[w], p2[w]);
        }
        if (VW == 2) {
            ushort2 t0v; t0v.x = p0[0]; t0v.y = p0[1]; *(ushort2*)(z0 + o) = t0v;
            ushort2 t1v; t1v.x = p1[0]; t1v.y = p1[1]; *(ushort2*)(z1 + o) = t1v;
            if (NT == 3) { ushort2 t2v; t2v.x = p2[0]; t2v.y = p2[1]; *(ushort2*)(z2 + o) = t2v; }
        } else {
            z0[o] = p0[0]; z1[o] = p1[0];
            if (NT == 3) z2[o] = p2[0];
        }
    }
}

template<int NT>
__launch_bounds__(512)
__global__ void agg_gemm(const float* __restrict__ h, const float* __restrict__ At,
                         const float* __restrict__ eps, int l,
                         ushort* __restrict__ z0, ushort* __restrict__ z1,
                         ushort* __restrict__ z2) {
    int g = blockIdx.x;
    int strip = blockIdx.y;                            // 0,1: VW2; 2: VW1 tail
    int lane = threadIdx.x & 63;
    int wave = threadIdx.x >> 6;                       // 0..7
    int rb = __builtin_amdgcn_readfirstlane(wave * 13); // 0,13,...,91
    const float* Ag = At + (size_t)g * NPG * NPG;
    const float* hg = h + (size_t)g * NPG * EMBP;
    float ep = 1.f + eps[l];

    if (strip < 2) {
        int c0 = strip * 128 + lane * 2;
        if (wave < 7) agg_rows<NT, 13, 2>(hg, Ag, rb, c0, ep, g, z0, z1, z2);
        else          agg_rows<NT, 9, 2>(hg, Ag, rb, c0, ep, g, z0, z1, z2);
    } else {
        int c0 = 256 + lane;
        if (wave < 7) agg_rows<NT, 13, 1>(hg, Ag, rb, c0, ep, g, z0, z1, z2);
        else          agg_rows<NT, 9, 1>(hg, Ag, rb, c0, ep, g, z0, z1, z2);
    }
}

// ============================================================================
// edge score from stacked uv buffer: relu(u[src]+v[dst]+b1) . W2 + b2
// uv row layout: [0:1216) = u, [1216:2432) = v
// ============================================================================
__global__ void edge_score(const float* __restrict__ uv, const float* __restrict__ b1,
                           const float* __restrict__ W2, const float* __restrict__ b2,
                           const int* __restrict__ src, const int* __restrict__ dst,
                           float* __restrict__ score, int E, int node_base) {
    int e = blockIdx.x * 4 + (threadIdx.x >> 6);
    int lane = threadIdx.x & 63;
    if (e >= E) return;
    const float* up = uv + (size_t)(src[e] - node_base) * UVM;
    const float* vp = uv + (size_t)(dst[e] - node_base) * UVM + 1216;
    float acc = 0.f;
    for (int j = lane; j < H4; j += 64) {
        float hj = fmaxf(up[j] + vp[j] + b1[j], 0.f);
        acc += hj * W2[j];
    }
#pragma unroll
    for (int o = 32; o > 0; o >>= 1) acc += __shfl_down(acc, o, 64);
    if (lane == 0) score[e] = acc + b2[0];
}

// ============================================================================
// per-graph top-125 of 500 contiguous edges via bitonic sort
// ============================================================================
__global__ void topk_kernel(const float* __restrict__ score, const int* __restrict__ src,
                            const int* __restrict__ dst, int* __restrict__ c_src,
                            int* __restrict__ c_dst, float* __restrict__ c_w,
                            float* __restrict__ mask) {
    __shared__ float s[512];
    __shared__ short sidx[512];
    int g = blockIdx.x, t = threadIdx.x;
    int base = g * EPG;
    s[t] = (t < EPG) ? score[base + t] : -1e30f;
    sidx[t] = (short)t;
    __syncthreads();
    for (int k = 2; k <= 512; k <<= 1) {
        for (int j = k >> 1; j > 0; j >>= 1) {
            int ixj = t ^ j;
            if (ixj > t) {
                float a = s[t], b = s[ixj];
                bool desc = ((t & k) == 0);
                if (desc ? (a < b) : (a > b)) {
                    s[t] = b; s[ixj] = a;
                    short tmp = sidx[t]; sidx[t] = sidx[ixj]; sidx[ixj] = tmp;
                }
            }
            __syncthreads();
        }
    }
    if (t < TOPK) {
        int e = base + sidx[t];
        int sn = src[e], dn = dst[e];
        c_src[g * TOPK + t] = sn;
        c_dst[g * TOPK + t] = dn;
        c_w[g * TOPK + t] = 1.f / (1.f + expf(-s[t]));
        mask[sn] = 1.f;
        mask[dn] = 1.f;
    }
}

// ============================================================================
// masked mean pool + linear head (h stride EMBP)
// ============================================================================
__global__ void pool_pred(const float* __restrict__ hc, const float* __restrict__ mask,
                          const float* __restrict__ W, const float* __restrict__ b,
                          float* __restrict__ out) {
    int g = blockIdx.x, t = threadIdx.x;
    __shared__ float mloc[NPG];
    __shared__ float pooled[EMB];
    __shared__ float cnt;
    if (t < NPG) mloc[t] = mask[g * NPG + t];
    __syncthreads();
    if (t == 0) {
        float c = 0.f;
        for (int n = 0; n < NPG; ++n) c += mloc[n];
        cnt = fmaxf(c, 1.f);
    }
    __syncthreads();
    for (int c0 = t; c0 < EMB; c0 += 256) {
        float acc = 0.f;
        for (int n = 0; n < NPG; ++n)
            acc += mloc[n] * hc[((size_t)g * NPG + n) * EMBP + c0];
        pooled[c0] = acc / cnt;
    }
    __syncthreads();
    if (t < NOUT) {
        float acc = b[t];
        for (int c0 = 0; c0 < EMB; ++c0) acc += pooled[c0] * W[c0 * NOUT + t];
        out[g * NOUT + t] = acc;
    }
}

// ============================================================================
extern "C" void kernel_launch(void* const* d_in, const int* in_sizes, int n_in,
                              void* d_out, int out_size, void* d_ws, size_t ws_size,
                              hipStream_t stream) {
    const float* x        = (const float*)d_in[0];
    const int*   eidx     = (const int*)d_in[1];
    const float* enc_in_W = (const float*)d_in[4];
    const float* enc_in_b = (const float*)d_in[5];
    const float* enc_W1   = (const float*)d_in[6];
    const float* enc_b1   = (const float*)d_in[7];
    const float* enc_W2   = (const float*)d_in[8];
    const float* enc_b2   = (const float*)d_in[9];
    const float* enc_eps  = (const float*)d_in[10];
    const float* att_W1   = (const float*)d_in[11];
    const float* att_b1   = (const float*)d_in[12];
    const float* att_W2   = (const float*)d_in[13];
    const float* att_b2   = (const float*)d_in[14];
    const float* clf_in_W = (const float*)d_in[15];
    const float* clf_in_b = (const float*)d_in[16];
    const float* clf_W1   = (const float*)d_in[17];
    const float* clf_b1   = (const float*)d_in[18];
    const float* clf_W2   = (const float*)d_in[19];
    const float* clf_b2   = (const float*)d_in[20];
    const float* clf_eps  = (const float*)d_in[21];
    const float* pred_W   = (const float*)d_in[22];
    const float* pred_b   = (const float*)d_in[23];
    float* out = (float*)d_out;

    const int* src = eidx;
    const int* dst = eidx + N_EDGES;

    // ---------------- workspace layout (ws_size = 256 MiB per harness poison) ----
    char* ws = (char*)d_ws;
    constexpr size_t SZ_H    = (size_t)NPAD * EMBP * 4;        //  25,722,880
    constexpr size_t SZ_ZP   = (size_t)NPAD * EMBP * 2;        //  12,861,440 per plane
    constexpr size_t SZ_TP   = (size_t)NPAD * H2P * 2;         //  25,722,880 per plane (FULL)
    constexpr size_t SZ_WSP  = (size_t)H2P * EMBP * 2;         //     409,600 per plane
    constexpr size_t SZ_WUVP = (size_t)UVM * EMBP * 2;         //   1,556,480 per plane

    constexpr size_t OFF_H   = 0;
    constexpr size_t OFF_Z   = OFF_H + SZ_H;                   //  25,722,880
    constexpr size_t OFF_T   = OFF_Z + 3 * SZ_ZP;              //  64,307,200
    constexpr size_t OFF_WSL = OFF_T + 3 * SZ_TP;              // 141,475,840
    constexpr size_t OFF_AT  = OFF_WSL + 6 * SZ_WSP;           // 143,933,440
    constexpr size_t OFF_SC  = OFF_AT + (size_t)N_GRAPHS * NPG * NPG * 4;  // 151,933,440
    constexpr size_t OFF_CW  = OFF_SC + (size_t)N_EDGES * 4;
    constexpr size_t OFF_MK  = OFF_CW + (size_t)N_GRAPHS * TOPK * 4;
    constexpr size_t OFF_CS  = OFF_MK + (size_t)N_NODES * 4;
    constexpr size_t OFF_CD  = OFF_CS + (size_t)N_GRAPHS * TOPK * 4;
    constexpr size_t OFF_UV  = OFF_CD + (size_t)N_GRAPHS * TOPK * 4;       // 152,713,440
    // uvbuf = UVROWS x UVM x 4 = 98,369,536 -> ends 251,082,976
    constexpr size_t OFF_WALL = 251083008;                     // aligned; wall <= 12,288,000 B
    // high water 263,371,008 < 268,435,456 (256 MiB)

    float*  h   = (float*)(ws + OFF_H);
    ushort* z0  = (ushort*)(ws + OFF_Z);
    ushort* z1  = (ushort*)(ws + OFF_Z + SZ_ZP);
    ushort* z2  = (ushort*)(ws + OFF_Z + 2 * SZ_ZP);
    ushort* t0  = (ushort*)(ws + OFF_T);
    ushort* t1  = (ushort*)(ws + OFF_T + SZ_TP);
    ushort* t2  = (ushort*)(ws + OFF_T + 2 * SZ_TP);
    ushort* w0p[3] = {(ushort*)(ws + OFF_WSL), (ushort*)(ws + OFF_WSL + SZ_WSP),
                      (ushort*)(ws + OFF_WSL + 2 * SZ_WSP)};
    float*  At    = (float*)(ws + OFF_AT);
    float*  score = (float*)(ws + OFF_SC);
    float*  c_w   = (float*)(ws + OFF_CW);
    float*  mask  = (float*)(ws + OFF_MK);
    int*    c_src = (int*)(ws + OFF_CS);
    int*    c_dst = (int*)(ws + OFF_CD);
    float*  uvbuf = (float*)(ws + OFF_UV);
    ushort* wall  = (ushort*)(ws + OFF_WALL);

    // overlays
    ushort* xp[3] = {z0, z1, z2};              // x planes live in z region pre-layers
    // phase S: wuv planes live in the (dead) t region
    ushort* wuvp[3] = {(ushort*)(ws + OFF_T), (ushort*)(ws + OFF_T + SZ_WUVP),
                       (ushort*)(ws + OFF_T + 2 * SZ_WUVP)};

    // ================= Phase E: encoder (NT=3) =================
    conv_w<3><<<(EMBP * 64) / 256, 256, 0, stream>>>(enc_in_W, D_IN, EMB, 64, EMBP,
                                                     w0p[0], w0p[1], w0p[2]);
    conv_a<3><<<(int)(((long)NPAD * 64) / 256), 256, 0, stream>>>(
        x, N_NODES, D_IN, D_IN, 64, xp[0], xp[1], xp[2], (long)NPAD * 64);
    conv_stack<3><<<cdiv(NLAYERS * 2 * T1W, 256), 256, 0, stream>>>(enc_W1, enc_W2, wall);
    mfma_gemm<3, 0, 0, 64><<<dim3(EMBP / 64, NPAD / 128), 256, 0, stream>>>(
        xp[0], xp[1], xp[2], w0p[0], w0p[1], w0p[2], enc_in_b, 64, EMB, EMBP,
        h, nullptr, nullptr, nullptr);

    hipMemsetAsync(At, 0, (size_t)N_GRAPHS * NPG * NPG * 4, stream);
    build_At<<<cdiv(N_EDGES, 256), 256, 0, stream>>>(src, dst, nullptr, At, N_EDGES);

    for (int l = 0; l < NLAYERS; ++l) {
        ushort* wl = wall + (size_t)l * 6 * T1W;               // NT=3: 3 W1 planes + 3 W2 planes
        agg_gemm<3><<<dim3(N_GRAPHS, 3), 512, 0, stream>>>(h, At, enc_eps, l, z0, z1, z2);
        mfma_gemm<3, 1, 1, 128><<<dim3(H2P / 128, NPAD / 128), 256, 0, stream>>>(
            z0, z1, z2, wl, wl + T1W, wl + 2 * T1W, enc_b1 + l * H2, EMBP, H2, H2P,
            nullptr, t0, t1, t2);
        if (l < NLAYERS - 1)
            mfma_gemm<3, 1, 0, 64><<<dim3(EMBP / 64, NPAD / 128), 256, 0, stream>>>(
                t0, t1, t2, wl + 3 * T1W, wl + 4 * T1W, wl + 5 * T1W,
                enc_b2 + l * EMB, H2P, EMB, EMBP, h, nullptr, nullptr, nullptr);
        else   // final layer: emit bf16 planes (no relu) straight into z region
            mfma_gemm<3, 0, 1, 64><<<dim3(EMBP / 64, NPAD / 128), 256, 0, stream>>>(
                t0, t1, t2, wl + 3 * T1W, wl + 4 * T1W, wl + 5 * T1W,
                enc_b2 + l * EMB, H2P, EMB, EMBP, nullptr, z0, z1, z2);
    }

    // ================= Phase S: edge scores + topk (2 chunks) =================
    conv_uv<<<cdiv(UVM * EMBP, 256), 256, 0, stream>>>(att_W1, wuvp[0], wuvp[1], wuvp[2]);
    for (int sc = 0; sc < 2; ++sc) {
        size_t nb0 = (size_t)sc * 10000;           // node base (0 / 10000)
        mfma_gemm<3, 0, 0, 128><<<dim3(UVM / 128, UVROWS / 128), 256, 0, stream>>>(
            z0 + nb0 * EMBP, z1 + nb0 * EMBP, z2 + nb0 * EMBP,
            wuvp[0], wuvp[1], wuvp[2], nullptr, EMBP, UVM, UVM,
            uvbuf, nullptr, nullptr, nullptr);
        edge_score<<<cdiv(N_EDGES / 2, 4), 256, 0, stream>>>(
            uvbuf, att_b1, att_W2, att_b2, src + sc * 50000, dst + sc * 50000,
            score + sc * 50000, N_EDGES / 2, (int)nb0);
    }
    hipMemsetAsync(mask, 0, N_NODES * 4, stream);
    topk_kernel<<<N_GRAPHS, 512, 0, stream>>>(score, src, dst, c_src, c_dst, c_w, mask);

    // ================= Phase C: classifier (NT=2) =================
    conv_w<2><<<(EMBP * 64) / 256, 256, 0, stream>>>(clf_in_W, D_IN, EMB, 64, EMBP,
                                                     w0p[0], w0p[1], w0p[2]);
    conv_a<2><<<(int)(((long)NPAD * 64) / 256), 256, 0, stream>>>(
        x, N_NODES, D_IN, D_IN, 64, xp[0], xp[1], nullptr, (long)NPAD * 64);
    conv_stack<2><<<cdiv(NLAYERS * 2 * T1W, 256), 256, 0, stream>>>(clf_W1, clf_W2, wall);
    mfma_gemm<2, 0, 0, 64><<<dim3(EMBP / 64, NPAD / 128), 256, 0, stream>>>(
        xp[0], xp[1], nullptr, w0p[0], w0p[1], nullptr, clf_in_b, 64, EMB, EMBP,
        h, nullptr, nullptr, nullptr);

    hipMemsetAsync(At, 0, (size_t)N_GRAPHS * NPG * NPG * 4, stream);
    build_At<<<cdiv(N_GRAPHS * TOPK, 256), 256, 0, stream>>>(c_src, c_dst, c_w, At,
                                                             N_GRAPHS * TOPK);

    for (int l = 0; l < NLAYERS; ++l) {
        ushort* wl = wall + (size_t)l * 4 * T1W;               // NT=2: 2 W1 planes + 2 W2 planes
        agg_gemm<2><<<dim3(N_GRAPHS, 3), 512, 0, stream>>>(h, At, clf_eps, l,
                                                           z0, z1, nullptr);
        mfma_gemm<2, 1, 1, 128><<<dim3(H2P / 128, NPAD / 128), 256, 0, stream>>>(
            z0, z1, nullptr, wl, wl + T1W, nullptr, clf_b1 + l * H2, EMBP, H2, H2P,
            nullptr, t0, t1, nullptr);
        if (l < NLAYERS - 1)
            mfma_gemm<2, 1, 0, 64><<<dim3(EMBP / 64, NPAD / 128), 256, 0, stream>>>(
                t0, t1, nullptr, wl + 2 * T1W, wl + 3 * T1W, nullptr,
                clf_b2 + l * EMB, H2P, EMB, EMBP, h, nullptr, nullptr, nullptr);
        else
            mfma_gemm<2, 0, 0, 64><<<dim3(EMBP / 64, NPAD / 128), 256, 0, stream>>>(
                t0, t1, nullptr, wl + 2 * T1W, wl + 3 * T1W, nullptr,
                clf_b2 + l * EMB, H2P, EMB, EMBP, h, nullptr, nullptr, nullptr);
    }

    // ================= pool + head =================
    pool_pred<<<N_GRAPHS, 256, 0, stream>>>(h, mask, pred_W, pred_b, out);
}